// Round 3
// baseline (274.419 us; speedup 1.0000x reference)
//
#include <hip/hip_runtime.h>
#include <math.h>

#define NN 4096
#define NE 16384
#define NG 64

// ---- ws layout (float offsets) ----
#define OFF_DEG   0         // 4096
#define OFF_ST1   4096      // 64
#define OFF_ST2   4160      // 128
#define OFF_ST3   4288      // 256
#define OFF_POOL  4544      // 64*128 = 8192
#define ZERO_FLOATS 12736   // everything above gets zeroed (51KB)
#define OFF_H1    12736     // 4096*32
#define OFF_H2    143808    // 4096*64
#define OFF_H3    405952    // 4096*128
#define OFF_WX1   930240    // 16*320
#define OFF_WX2   935360    // 32*640
#define OFF_WX3   955840    // 64*1280
#define OFF_Y     1037760   // up to 4096*1152

// ---------------- prep: build Wext = [We | be | Wr] (K x 10C) + degree ----------------
__device__ __forceinline__ void build_wext(const float* We, const float* be,
                                           const float* Wr, float* Wx,
                                           int CIN, int C, int t) {
    int NC = 10 * C;
    int i = t / NC; int col = t - i * NC;
    float v;
    if (col < 8 * C)      { int f = col / C, o = col - f * C; v = We[f * CIN * C + o * CIN + i]; }
    else if (col < 9 * C) { int o = col - 8 * C;              v = be[o * CIN + i]; }
    else                  { int o = col - 9 * C;              v = Wr[i * C + o]; }
    Wx[t] = v;
}

__global__ __launch_bounds__(256) void k_prep(
    const float* __restrict__ We1, const float* __restrict__ be1, const float* __restrict__ Wr1,
    const float* __restrict__ We2, const float* __restrict__ be2, const float* __restrict__ Wr2,
    const float* __restrict__ We3, const float* __restrict__ be3, const float* __restrict__ Wr3,
    const int* __restrict__ ei, float* __restrict__ ws)
{
    int t = blockIdx.x * 256 + threadIdx.x;
    if (t < 5120)  { build_wext(We1, be1, Wr1, ws + OFF_WX1, 16, 32, t); return; }
    t -= 5120;
    if (t < 20480) { build_wext(We2, be2, Wr2, ws + OFF_WX2, 32, 64, t); return; }
    t -= 20480;
    if (t < 81920) { build_wext(We3, be3, Wr3, ws + OFF_WX3, 64, 128, t); return; }
    t -= 81920;
    if (t < NE)    { atomicAdd(&ws[OFF_DEG + ei[t]], 1.0f); }
}

// ---------------- proj GEMM: [Y | h] = bn_prelu(A) @ [Wcat | Wr] ----------------
// BM=64, BN=64, 256 threads, 4x4/thread. K fully staged. Cols >= 9C go to h
// with +bias+br (h init for the egather atomics). BN+PReLU of the PREVIOUS
// layer folded into the A-staging.
template<int K, int C, bool BN>
__global__ __launch_bounds__(256) void k_proj(
    const float* __restrict__ A, const float* __restrict__ Bw,
    const float* __restrict__ st, const float* __restrict__ bg,
    const float* __restrict__ bb, const float* __restrict__ alpha,
    const float* __restrict__ bias, const float* __restrict__ br,
    float* __restrict__ Y, float* __restrict__ h)
{
    constexpr int NC = 10 * C;
    __shared__ float sA[K][68];
    __shared__ float sB[K][68];
    __shared__ float sS[K], sT[K];
    const int tid = threadIdx.x;
    const int m0 = blockIdx.x * 64;
    const int n0 = blockIdx.y * 64;

    float al = 0.f;
    if constexpr (BN) {
        if (tid < K) {
            float mean = st[tid] * (1.f / NN);
            float var  = st[K + tid] * (1.f / NN) - mean * mean;
            var = fmaxf(var, 0.f);
            float s = rsqrtf(var + 1e-5f) * bg[tid];
            sS[tid] = s; sT[tid] = bb[tid] - mean * s;
        }
        al = alpha[0];
        __syncthreads();
    }
    for (int t = tid; t < 64 * K; t += 256) {
        int m = t / K, i = t - m * K;
        float v = A[(m0 + m) * K + i];
        if constexpr (BN) { v = sS[i] * v + sT[i]; v = v >= 0.f ? v : al * v; }
        sA[i][m] = v;
    }
    for (int t = tid; t < 64 * K; t += 256) {
        int i = t / 64, n = t - i * 64;
        sB[i][n] = Bw[i * NC + n0 + n];
    }
    __syncthreads();

    const int tn = tid % 16, tm = tid / 16;
    float acc[4][4] = {{0.f}};
#pragma unroll 8
    for (int i = 0; i < K; ++i) {
        float4 a = *(const float4*)&sA[i][tm * 4];
        float4 b = *(const float4*)&sB[i][tn * 4];
        acc[0][0] += a.x * b.x; acc[0][1] += a.x * b.y; acc[0][2] += a.x * b.z; acc[0][3] += a.x * b.w;
        acc[1][0] += a.y * b.x; acc[1][1] += a.y * b.y; acc[1][2] += a.y * b.z; acc[1][3] += a.y * b.w;
        acc[2][0] += a.z * b.x; acc[2][1] += a.z * b.y; acc[2][2] += a.z * b.z; acc[2][3] += a.z * b.w;
        acc[3][0] += a.w * b.x; acc[3][1] += a.w * b.y; acc[3][2] += a.w * b.z; acc[3][3] += a.w * b.w;
    }

    if (n0 + 64 <= 9 * C) {            // pure-Y block: vector stores
#pragma unroll
        for (int mm = 0; mm < 4; ++mm) {
            int m = m0 + tm * 4 + mm;
            float4 v = make_float4(acc[mm][0], acc[mm][1], acc[mm][2], acc[mm][3]);
            *(float4*)&Y[(size_t)m * (9 * C) + n0 + tn * 4] = v;
        }
    } else if (n0 >= 9 * C) {          // pure-residual block: init h
        int o = n0 - 9 * C + tn * 4;
        float4 add = *(const float4*)&bias[o];
        float4 ad2 = *(const float4*)&br[o];
#pragma unroll
        for (int mm = 0; mm < 4; ++mm) {
            int m = m0 + tm * 4 + mm;
            float4 v = make_float4(acc[mm][0] + add.x + ad2.x, acc[mm][1] + add.y + ad2.y,
                                   acc[mm][2] + add.z + ad2.z, acc[mm][3] + add.w + ad2.w);
            *(float4*)&h[(size_t)m * C + o] = v;
        }
    } else {                           // mixed block (C=32 only): scalar
#pragma unroll
        for (int mm = 0; mm < 4; ++mm) {
            int m = m0 + tm * 4 + mm;
#pragma unroll
            for (int nn = 0; nn < 4; ++nn) {
                int col = n0 + tn * 4 + nn;
                if (col < 9 * C) Y[(size_t)m * (9 * C) + col] = acc[mm][nn];
                else { int o = col - 9 * C; h[(size_t)m * C + o] = acc[mm][nn] + bias[o] + br[o]; }
            }
        }
    }
}

// ---------------- per-edge gather (float4): h[dst] += norm[src]*sum_f ea'[f]*Y[src,f,:] ----------------
template<int C>
__global__ __launch_bounds__(256) void k_egather(
    const float* __restrict__ Y, const float* __restrict__ eattr,
    const int* __restrict__ ei, const float* __restrict__ deg,
    float* __restrict__ h)
{
    constexpr int Q = C / 4;
    int idx = blockIdx.x * 256 + threadIdx.x;
    int e = idx / Q;
    int q = idx - e * Q;
    int src = ei[e], dst = ei[NE + e];
    float d = deg[src];
    float nrm = d > 0.f ? 1.f / d : 0.f;
    const float4* y = (const float4*)(Y + (size_t)src * (9 * C));
    const float* ea = eattr + e * 8;
    float4 acc = y[8 * Q + q];          // be-term (ea'=1)
#pragma unroll
    for (int f = 0; f < 8; ++f) {
        float4 yf = y[f * Q + q];
        float w = ea[f];
        acc.x += w * yf.x; acc.y += w * yf.y; acc.z += w * yf.z; acc.w += w * yf.w;
    }
    float* hp = h + (size_t)dst * C + q * 4;
    atomicAdd(hp + 0, acc.x * nrm);
    atomicAdd(hp + 1, acc.y * nrm);
    atomicAdd(hp + 2, acc.z * nrm);
    atomicAdd(hp + 3, acc.w * nrm);
}

// ---------------- BN stats: per-channel sum / sumsq of h ----------------
template<int C>
__global__ __launch_bounds__(256) void k_bnstat(const float* __restrict__ h, float* __restrict__ st)
{
    constexpr int NL = 256 / C;
    __shared__ float sred[256];
    const int tid = threadIdx.x;
    const int o = tid % C, nl = tid / C;
    const int rbase = blockIdx.x * 64;
    float sum = 0.f, sq = 0.f;
    for (int r = nl; r < 64; r += NL) {
        float v = h[(size_t)(rbase + r) * C + o];
        sum += v; sq += v * v;
    }
    sred[tid] = sum;
    __syncthreads();
    if (tid < C) {
        float s = 0.f;
        for (int g2 = 0; g2 < NL; ++g2) s += sred[g2 * C + tid];
        atomicAdd(&st[tid], s);
    }
    __syncthreads();
    sred[tid] = sq;
    __syncthreads();
    if (tid < C) {
        float s = 0.f;
        for (int g2 = 0; g2 < NL; ++g2) s += sred[g2 * C + tid];
        atomicAdd(&st[C + tid], s);
    }
}

// ---------------- gated pooling, BN3+PReLU folded into the load ----------------
__global__ __launch_bounds__(256) void k_pool(
    const float* __restrict__ h3, const int* __restrict__ batch,
    const float* __restrict__ st, const float* __restrict__ bg,
    const float* __restrict__ bb, const float* __restrict__ alpha,
    const float* __restrict__ Wi, const float* __restrict__ bi,
    const float* __restrict__ Wj, const float* __restrict__ bj,
    float* __restrict__ pooled)
{
    constexpr int KN = 8, NB = 16;
    __shared__ float sH[NB * 128];
    __shared__ float sS[128], sT[128];
    __shared__ int sB[NB];
    const int tid = threadIdx.x;
    const int nbase = blockIdx.x * NB;
    if (tid < 128) {
        float mean = st[tid] * (1.f / NN);
        float var  = st[128 + tid] * (1.f / NN) - mean * mean;
        var = fmaxf(var, 0.f);
        float s = rsqrtf(var + 1e-5f) * bg[tid];
        sS[tid] = s; sT[tid] = bb[tid] - mean * s;
    }
    float al = alpha[0];
    __syncthreads();
    for (int t = tid; t < NB * 128; t += 256) {
        int i = t % 128;
        float v = sS[i] * h3[(size_t)nbase * 128 + t] + sT[i];
        sH[t] = v >= 0.f ? v : al * v;
    }
    if (tid < NB) sB[tid] = batch[nbase + tid];
    __syncthreads();

    const int o = tid % 128, nl = tid / 128;
    float gacc[KN], facc[KN];
#pragma unroll
    for (int k = 0; k < KN; ++k) { gacc[k] = 0.f; facc[k] = 0.f; }
    for (int i = 0; i < 128; ++i) {
        float wi = Wi[i * 128 + o], wj = Wj[i * 128 + o];
#pragma unroll
        for (int k = 0; k < KN; ++k) {
            float hv = sH[(nl * KN + k) * 128 + i];
            gacc[k] += hv * wi;
            facc[k] += hv * wj;
        }
    }
    float bio = bi[o], bjo = bj[o];
#pragma unroll
    for (int k = 0; k < KN; ++k) {
        int r = nl * KN + k;
        float gate = 1.f / (1.f + expf(-(gacc[k] + bio)));
        float feat = tanhf(facc[k] + bjo);
        atomicAdd(&pooled[sB[r] * 128 + o], gate * feat);
    }
}

// ---------------- final: tanh(pooled) @ Wfc + bfc, split halves ----------------
__global__ __launch_bounds__(256) void k_final(
    const float* __restrict__ pooled, const float* __restrict__ Wfc,
    const float* __restrict__ bfc, float* __restrict__ out)
{
    __shared__ float sP[128];
    const int g = blockIdx.x, c = threadIdx.x;
    if (c < 128) sP[c] = tanhf(pooled[g * 128 + c]);
    __syncthreads();
    float z = bfc[c];
    for (int i = 0; i < 128; ++i) z += sP[i] * Wfc[i * 256 + c];
    int oidx = (c < 128) ? (g * 128 + c) : (NG * 128 + g * 128 + (c - 128));
    out[oidx] = z;
}

extern "C" void kernel_launch(void* const* d_in, const int* in_sizes, int n_in,
                              void* d_out, int out_size, void* d_ws, size_t ws_size,
                              hipStream_t stream)
{
    (void)in_sizes; (void)n_in; (void)out_size; (void)ws_size;
    const float* x     = (const float*)d_in[0];
    const float* eattr = (const float*)d_in[1];
    const int*   ei    = (const int*)d_in[2];
    const int*   batch = (const int*)d_in[3];
    const float* We1 = (const float*)d_in[4];
    const float* be1 = (const float*)d_in[5];
    const float* bias1 = (const float*)d_in[6];
    const float* Wr1 = (const float*)d_in[7];
    const float* br1 = (const float*)d_in[8];
    const float* bg1 = (const float*)d_in[9];
    const float* bb1 = (const float*)d_in[10];
    const float* a1  = (const float*)d_in[11];
    const float* We2 = (const float*)d_in[12];
    const float* be2 = (const float*)d_in[13];
    const float* bias2 = (const float*)d_in[14];
    const float* Wr2 = (const float*)d_in[15];
    const float* br2 = (const float*)d_in[16];
    const float* bg2 = (const float*)d_in[17];
    const float* bb2 = (const float*)d_in[18];
    const float* a2  = (const float*)d_in[19];
    const float* We3 = (const float*)d_in[20];
    const float* be3 = (const float*)d_in[21];
    const float* bias3 = (const float*)d_in[22];
    const float* Wr3 = (const float*)d_in[23];
    const float* br3 = (const float*)d_in[24];
    const float* bg3 = (const float*)d_in[25];
    const float* bb3 = (const float*)d_in[26];
    const float* a3  = (const float*)d_in[27];
    const float* Wi  = (const float*)d_in[28];
    const float* bi  = (const float*)d_in[29];
    const float* Wj  = (const float*)d_in[30];
    const float* bj  = (const float*)d_in[31];
    const float* Wfc = (const float*)d_in[32];
    const float* bfc = (const float*)d_in[33];
    float* ws  = (float*)d_ws;
    float* out = (float*)d_out;

    hipMemsetAsync(d_ws, 0, (size_t)ZERO_FLOATS * sizeof(float), stream);
    k_prep<<<484, 256, 0, stream>>>(We1, be1, Wr1, We2, be2, Wr2, We3, be3, Wr3, ei, ws);

    // layer 1: K=16, C=32 (no BN on input x)
    k_proj<16, 32, false><<<dim3(64, 5), 256, 0, stream>>>(
        x, ws + OFF_WX1, nullptr, nullptr, nullptr, nullptr, bias1, br1, ws + OFF_Y, ws + OFF_H1);
    k_egather<32><<<NE * 8 / 256, 256, 0, stream>>>(ws + OFF_Y, eattr, ei, ws + OFF_DEG, ws + OFF_H1);
    k_bnstat<32><<<64, 256, 0, stream>>>(ws + OFF_H1, ws + OFF_ST1);

    // layer 2: K=32, C=64 (BN1+PReLU folded into A-load)
    k_proj<32, 64, true><<<dim3(64, 10), 256, 0, stream>>>(
        ws + OFF_H1, ws + OFF_WX2, ws + OFF_ST1, bg1, bb1, a1, bias2, br2, ws + OFF_Y, ws + OFF_H2);
    k_egather<64><<<NE * 16 / 256, 256, 0, stream>>>(ws + OFF_Y, eattr, ei, ws + OFF_DEG, ws + OFF_H2);
    k_bnstat<64><<<64, 256, 0, stream>>>(ws + OFF_H2, ws + OFF_ST2);

    // layer 3: K=64, C=128 (BN2+PReLU folded)
    k_proj<64, 128, true><<<dim3(64, 20), 256, 0, stream>>>(
        ws + OFF_H2, ws + OFF_WX3, ws + OFF_ST2, bg2, bb2, a2, bias3, br3, ws + OFF_Y, ws + OFF_H3);
    k_egather<128><<<NE * 32 / 256, 256, 0, stream>>>(ws + OFF_Y, eattr, ei, ws + OFF_DEG, ws + OFF_H3);
    k_bnstat<128><<<64, 256, 0, stream>>>(ws + OFF_H3, ws + OFF_ST3);

    // pooling (BN3+PReLU folded) + head
    k_pool<<<NN / 16, 256, 0, stream>>>(ws + OFF_H3, batch, ws + OFF_ST3, bg3, bb3, a3,
                                        Wi, bi, Wj, bj, ws + OFF_POOL);
    k_final<<<NG, 256, 0, stream>>>(ws + OFF_POOL, Wfc, bfc, out);
}